// Round 10
// baseline (867.879 us; speedup 1.0000x reference)
//
#include <hip/hip_runtime.h>

// NodeNetwork persistent-pipelined kernel: 256 threads (4 waves), 64-node tiles,
// f16 x1/h1 in LDS (35.8KB -> 4 blocks/CU). Grid = 1024 (exactly 4/CU); each
// block loops 3-4 tiles. Tile k+1's mailbox streams under tile k's FMA phases
// (sched_barrier-pinned 8-load batches, R4/R8-proven) into macc regs; x2(k+1)
// lands in ldsB during tile k's tail. Prologue streams tile 0 uncovered.
// No launch_bounds min-waves (R7 lesson: catastrophic spills).
constexpr int NB = 64;
constexpr int THREADS = 256;
constexpr int X1SU = 66;   // x1 row stride in u32 (128 f16 + 4 pad)
constexpr int H1SU = 50;   // h1 row stride in u32 (96 f16 + 4 pad), aliases x1 region
constexpr int X2S  = 68;   // x2/h2 row stride (f32)

typedef __fp16 half2_t __attribute__((ext_vector_type(2)));

__device__ __forceinline__ float fast_tanh(float x) {
    // tanh(x) = 1 - 2/(exp(2x)+1); v_exp+v_rcp, abs err ~1e-6, saturates to +-1.
    float e = __expf(2.0f * x);
    return 1.0f - 2.0f * __builtin_amdgcn_rcpf(e + 1.0f);
}

__device__ __forceinline__ unsigned pk16(float a, float b) {
    half2_t h = __builtin_amdgcn_cvt_pkrtz(a, b);
    return __builtin_bit_cast(unsigned, h);
}

__device__ __forceinline__ void fma24(float x0, float x1, float x2, float x3,
                                      const float* __restrict__ w0,
                                      float* __restrict__ acc) {
    #pragma unroll
    for (int j = 0; j < 24; ++j) acc[j] = fmaf(x0, w0[j],       acc[j]);
    #pragma unroll
    for (int j = 0; j < 24; ++j) acc[j] = fmaf(x1, w0[96 + j],  acc[j]);
    #pragma unroll
    for (int j = 0; j < 24; ++j) acc[j] = fmaf(x2, w0[192 + j], acc[j]);
    #pragma unroll
    for (int j = 0; j < 24; ++j) acc[j] = fmaf(x3, w0[288 + j], acc[j]);
}

__device__ __forceinline__ void fma16(float x0, float x1, float x2, float x3,
                                      const float* __restrict__ w0,
                                      float* __restrict__ acc) {
    #pragma unroll
    for (int j = 0; j < 16; ++j) acc[j] = fmaf(x0, w0[j],       acc[j]);
    #pragma unroll
    for (int j = 0; j < 16; ++j) acc[j] = fmaf(x1, w0[64 + j],  acc[j]);
    #pragma unroll
    for (int j = 0; j < 16; ++j) acc[j] = fmaf(x2, w0[128 + j], acc[j]);
    #pragma unroll
    for (int j = 0; j < 16; ++j) acc[j] = fmaf(x3, w0[192 + j], acc[j]);
}

__global__ __launch_bounds__(THREADS) void node_net_kernel(
    const float* __restrict__ feat, const float* __restrict__ hid,
    const float* __restrict__ mail,
    const float* __restrict__ w1a, const float* __restrict__ b1a,
    const float* __restrict__ w1b, const float* __restrict__ b1b,
    const float* __restrict__ w2a, const float* __restrict__ b2a,
    const float* __restrict__ w2b, const float* __restrict__ b2b,
    float* __restrict__ out, int n_tiles)
{
    __shared__ unsigned ldsA[NB * X1SU];   // x1 f16, later h1 f16
    __shared__ float    ldsB[NB * X2S];    // x2, later h2 (f32)
    __shared__ float    ldsS[NB * 4];      // per-sub partial sumsq

    const int t    = threadIdx.x;
    const int c4   = t & 15;           // float4 column 0..15
    const int nb   = t >> 4;           // node base 0..15; owns nodes nb+16c (chains)
    const int node = t & 63;
    const int sub  = __builtin_amdgcn_readfirstlane(t >> 6);  // wave id 0..3, uniform
    const int base = blockIdx.x;
    const int nt   = (n_tiles - 1 - base) / 1024 + 1;   // tiles this block owns

    const float4* mail_f4 = reinterpret_cast<const float4*>(mail);

    float4 macc[4];

    // ---------- Prologue: stream mailbox(tile 0) -> macc -> ldsB (uncovered) ----------
    {
        const float4* mb = mail_f4 + ((size_t)base * NB + nb) * 256 + c4;
        #pragma unroll
        for (int i = 0; i < 4; ++i) macc[i] = make_float4(0.f, 0.f, 0.f, 0.f);
        #pragma unroll 1
        for (int j = 0; j < 8; ++j) {           // depth pairs (2j, 2j+1), 8 loads in flight
            float4 cur[8];
            #pragma unroll
            for (int c = 0; c < 4; ++c) {
                const float4* ch = mb + (size_t)c * 4096 + (size_t)(2 * j) * 16;
                cur[c]     = ch[0];
                cur[4 + c] = ch[16];
            }
            #pragma unroll
            for (int i = 0; i < 4; ++i) macc[i] += cur[i] + cur[4 + i];
        }
        #pragma unroll
        for (int i = 0; i < 4; ++i)
            *reinterpret_cast<float4*>(&ldsB[(nb + 16 * i) * X2S + c4 * 4]) = macc[i];
    }
    __syncthreads();                   // B0: x2(tile0) visible

    // ---------- Main loop over tiles ----------
    #pragma unroll 1
    for (int k = 0; k < nt; ++k) {
        const size_t n0 = (size_t)(base + 1024 * k) * NB;
        const bool hn = (k + 1 < nt);  // block-uniform
        const float4* mbN = hn
            ? mail_f4 + ((size_t)(base + 1024 * (k + 1)) * NB + nb) * 256 + c4
            : mail_f4 + nb * 256 + c4; // dummy (never loaded)

        // ---- P1: stage x1(k) = [feat|hid] as f16 -> ldsA ----
        #pragma unroll
        for (int i = 0; i < 4; ++i) {
            int n = nb + 16 * i;
            float4 f = reinterpret_cast<const float4*>(feat)[(n0 + n) * 16 + c4];
            float4 g = reinterpret_cast<const float4*>(hid )[(n0 + n) * 16 + c4];
            unsigned* dst = &ldsA[n * X1SU];
            *reinterpret_cast<uint2*>(dst + c4 * 2)      = make_uint2(pk16(f.x, f.y), pk16(f.z, f.w));
            *reinterpret_cast<uint2*>(dst + 32 + c4 * 2) = make_uint2(pk16(g.x, g.y), pk16(g.z, g.w));
        }
        __syncthreads();               // B1: x1 visible

        // ---- P2: h1 = relu(x1@w1a+b1a), 32 k4; stream mbN depths 0-7 ----
        float acc1[24];
        {
            const float* b = b1a + sub * 24;
            #pragma unroll
            for (int j = 0; j < 24; ++j) acc1[j] = b[j];
        }
        #pragma unroll
        for (int i = 0; i < 4; ++i) macc[i] = make_float4(0.f, 0.f, 0.f, 0.f);
        {
            const unsigned* xr = &ldsA[node * X1SU];
            #pragma unroll 1
            for (int bj = 0; bj < 4; ++bj) {          // depth pair (2bj, 2bj+1)
                float4 cur[8];
                if (hn) {
                    #pragma unroll
                    for (int c = 0; c < 4; ++c) {
                        const float4* ch = mbN + (size_t)c * 4096 + (size_t)(2 * bj) * 16;
                        cur[c]     = ch[0];
                        cur[4 + c] = ch[16];
                    }
                }
                __builtin_amdgcn_sched_barrier(0);    // pin: loads above
                #pragma unroll
                for (int kk = 0; kk < 8; ++kk) {
                    int k4 = bj * 8 + kk;
                    uint2 xu = *reinterpret_cast<const uint2*>(xr + 2 * k4);
                    half2_t p0 = __builtin_bit_cast(half2_t, xu.x);
                    half2_t p1 = __builtin_bit_cast(half2_t, xu.y);
                    fma24((float)p0.x, (float)p0.y, (float)p1.x, (float)p1.y,
                          w1a + (k4 * 4) * 96 + sub * 24, acc1);
                }
                __builtin_amdgcn_sched_barrier(0);    // pin: consume below
                if (hn) {
                    #pragma unroll
                    for (int i = 0; i < 4; ++i) macc[i] += cur[i] + cur[4 + i];
                }
            }
        }
        __syncthreads();               // B2: x1 reads done; reuse ldsA for h1
        {
            unsigned* hv = &ldsA[node * H1SU + sub * 12];
            #pragma unroll
            for (int p = 0; p < 12; ++p)
                hv[p] = pk16(fmaxf(acc1[2*p], 0.f), fmaxf(acc1[2*p + 1], 0.f));
        }
        __syncthreads();               // B3: h1 visible

        // ---- P3: r1 = tanh(h1@w1b+b1b), 24 k4; stream mbN depths 8-11 ----
        float r1v[16];
        {
            float acc[16];
            const float* b = b1b + sub * 16;
            #pragma unroll
            for (int j = 0; j < 16; ++j) acc[j] = b[j];
            const unsigned* hb = &ldsA[node * H1SU];
            #pragma unroll 1
            for (int bj = 0; bj < 2; ++bj) {          // depth pair (8+2bj, 9+2bj)
                float4 cur[8];
                if (hn) {
                    #pragma unroll
                    for (int c = 0; c < 4; ++c) {
                        const float4* ch = mbN + (size_t)c * 4096 + (size_t)(8 + 2 * bj) * 16;
                        cur[c]     = ch[0];
                        cur[4 + c] = ch[16];
                    }
                }
                __builtin_amdgcn_sched_barrier(0);
                #pragma unroll
                for (int kk = 0; kk < 12; ++kk) {
                    int k4 = bj * 12 + kk;
                    uint2 hu = *reinterpret_cast<const uint2*>(hb + 2 * k4);
                    half2_t p0 = __builtin_bit_cast(half2_t, hu.x);
                    half2_t p1 = __builtin_bit_cast(half2_t, hu.y);
                    fma16((float)p0.x, (float)p0.y, (float)p1.x, (float)p1.y,
                          w1b + (k4 * 4) * 64 + sub * 16, acc);
                }
                __builtin_amdgcn_sched_barrier(0);
                if (hn) {
                    #pragma unroll
                    for (int i = 0; i < 4; ++i) macc[i] += cur[i] + cur[4 + i];
                }
            }
            #pragma unroll
            for (int j = 0; j < 16; ++j) r1v[j] = fast_tanh(acc[j]);
        }

        // ---- P4: h2 = relu(x2@w2a+b2a), 16 k4; stream mbN depths 12-15 ----
        float h2v[16];
        {
            float acc[16];
            const float* b = b2a + sub * 16;
            #pragma unroll
            for (int j = 0; j < 16; ++j) acc[j] = b[j];
            const float4* xr = reinterpret_cast<const float4*>(&ldsB[node * X2S]);
            #pragma unroll 1
            for (int bj = 0; bj < 2; ++bj) {          // depth pair (12+2bj, 13+2bj)
                float4 cur[8];
                if (hn) {
                    #pragma unroll
                    for (int c = 0; c < 4; ++c) {
                        const float4* ch = mbN + (size_t)c * 4096 + (size_t)(12 + 2 * bj) * 16;
                        cur[c]     = ch[0];
                        cur[4 + c] = ch[16];
                    }
                }
                __builtin_amdgcn_sched_barrier(0);
                #pragma unroll
                for (int kk = 0; kk < 8; ++kk) {
                    int k4 = bj * 8 + kk;
                    float4 x = xr[k4];
                    fma16(x.x, x.y, x.z, x.w, w2a + (k4 * 4) * 64 + sub * 16, acc);
                }
                __builtin_amdgcn_sched_barrier(0);
                if (hn) {
                    #pragma unroll
                    for (int i = 0; i < 4; ++i) macc[i] += cur[i] + cur[4 + i];
                }
            }
            #pragma unroll
            for (int j = 0; j < 16; ++j) h2v[j] = fmaxf(acc[j], 0.f);
        }
        __syncthreads();               // B4: x2 & h1 reads done; reuse ldsB for h2
        {
            float4* hrow = reinterpret_cast<float4*>(&ldsB[node * X2S + sub * 16]);
            hrow[0] = make_float4(h2v[0],  h2v[1],  h2v[2],  h2v[3]);
            hrow[1] = make_float4(h2v[4],  h2v[5],  h2v[6],  h2v[7]);
            hrow[2] = make_float4(h2v[8],  h2v[9],  h2v[10], h2v[11]);
            hrow[3] = make_float4(h2v[12], h2v[13], h2v[14], h2v[15]);
        }
        __syncthreads();               // B5: h2 visible

        // ---- P5: r2 = tanh(h2@w2b+b2b), 16 k4 ----
        float r2v[16];
        {
            float acc[16];
            const float* b = b2b + sub * 16;
            #pragma unroll
            for (int j = 0; j < 16; ++j) acc[j] = b[j];
            const float4* hr = reinterpret_cast<const float4*>(&ldsB[node * X2S]);
            #pragma unroll 2
            for (int k4 = 0; k4 < 16; ++k4) {
                float4 x = hr[k4];
                fma16(x.x, x.y, x.z, x.w, w2b + (k4 * 4) * 64 + sub * 16, acc);
            }
            #pragma unroll
            for (int j = 0; j < 16; ++j) r2v[j] = fast_tanh(acc[j]);
        }
        __syncthreads();               // B6: h2 reads done (ldsB free for x2(k+1))

        // ---- P6: sumsq -> ldsS; park x2(k+1) -> ldsB ----
        float s = 0.f;
        #pragma unroll
        for (int j = 0; j < 16; ++j) s = fmaf(r1v[j], r1v[j], s);
        #pragma unroll
        for (int j = 0; j < 16; ++j) s = fmaf(r2v[j], r2v[j], s);
        ldsS[node * 4 + sub] = s;
        if (hn) {
            #pragma unroll
            for (int i = 0; i < 4; ++i)
                *reinterpret_cast<float4*>(&ldsB[(nb + 16 * i) * X2S + c4 * 4]) = macc[i];
        }
        __syncthreads();               // B7: sums + x2(k+1) visible
        float4 sv = reinterpret_cast<const float4*>(ldsS)[node];
        float rn = rsqrtf(sv.x + sv.y + sv.z + sv.w);

        float* orow = out + (n0 + node) * 128;
        float4* o1 = reinterpret_cast<float4*>(orow + sub * 16);
        float4* o2 = reinterpret_cast<float4*>(orow + 64 + sub * 16);
        #pragma unroll
        for (int j4 = 0; j4 < 4; ++j4) {
            o1[j4] = make_float4(r1v[j4*4+0]*rn, r1v[j4*4+1]*rn, r1v[j4*4+2]*rn, r1v[j4*4+3]*rn);
            o2[j4] = make_float4(r2v[j4*4+0]*rn, r2v[j4*4+1]*rn, r2v[j4*4+2]*rn, r2v[j4*4+3]*rn);
        }
        // next iter's P1 writes ldsA: safe (h1 reads ended at B4; B7 orders)
    }
}

extern "C" void kernel_launch(void* const* d_in, const int* in_sizes, int n_in,
                              void* d_out, int out_size, void* d_ws, size_t ws_size,
                              hipStream_t stream) {
    const float* feat = (const float*)d_in[0];
    const float* hid  = (const float*)d_in[1];
    const float* mail = (const float*)d_in[2];
    const float* w1a  = (const float*)d_in[3];
    const float* b1a  = (const float*)d_in[4];
    const float* w1b  = (const float*)d_in[5];
    const float* b1b  = (const float*)d_in[6];
    const float* w2a  = (const float*)d_in[7];
    const float* b2a  = (const float*)d_in[8];
    const float* w2b  = (const float*)d_in[9];
    const float* b2b  = (const float*)d_in[10];
    float* out = (float*)d_out;

    const int N = in_sizes[0] / 64;          // 200000
    const int n_tiles = N / NB;              // 3125
    const int blocks = 1024;                 // 4 per CU exactly; blocks loop tiles

    node_net_kernel<<<blocks, THREADS, 0, stream>>>(
        feat, hid, mail, w1a, b1a, w1b, b1b, w2a, b2a, w2b, b2b, out, n_tiles);
}

// Round 11
// 268.198 us; speedup vs baseline: 3.2360x; 3.2360x over previous
//
#include <hip/hip_runtime.h>

// NodeNetwork fused kernel: 64 nodes/block, 256 threads (4 waves), f16 x1/h1 LDS
// (35.8KB -> 4 blocks/CU). R8 structure (proven 239.9us) + ONE change: mailbox
// depth-rotation swizzle (d+nb)&15 so one load instr's 4 node-segments hit 4
// consecutive depths (4096+1024k byte offsets) instead of pure 4096k strides ->
// spreads L2/HBM channel classes. Sum over depths is order-invariant.
// No launch_bounds min-waves (R7 lesson). sched_barrier-pinned batches (R4-proven).
constexpr int NB = 64;
constexpr int THREADS = 256;
constexpr int X1SU = 66;   // x1 row stride in u32 (128 f16 + 4 pad)
constexpr int H1SU = 50;   // h1 row stride in u32 (96 f16 + 4 pad), aliases x1 region
constexpr int X2S  = 68;   // x2/h2 row stride (f32)

typedef __fp16 half2_t __attribute__((ext_vector_type(2)));

__device__ __forceinline__ float fast_tanh(float x) {
    // tanh(x) = 1 - 2/(exp(2x)+1); v_exp+v_rcp, abs err ~1e-6, saturates to +-1.
    float e = __expf(2.0f * x);
    return 1.0f - 2.0f * __builtin_amdgcn_rcpf(e + 1.0f);
}

__device__ __forceinline__ unsigned pk16(float a, float b) {
    half2_t h = __builtin_amdgcn_cvt_pkrtz(a, b);
    return __builtin_bit_cast(unsigned, h);
}

__device__ __forceinline__ void fma24(float x0, float x1, float x2, float x3,
                                      const float* __restrict__ w0,
                                      float* __restrict__ acc) {
    #pragma unroll
    for (int j = 0; j < 24; ++j) acc[j] = fmaf(x0, w0[j],       acc[j]);
    #pragma unroll
    for (int j = 0; j < 24; ++j) acc[j] = fmaf(x1, w0[96 + j],  acc[j]);
    #pragma unroll
    for (int j = 0; j < 24; ++j) acc[j] = fmaf(x2, w0[192 + j], acc[j]);
    #pragma unroll
    for (int j = 0; j < 24; ++j) acc[j] = fmaf(x3, w0[288 + j], acc[j]);
}

__device__ __forceinline__ void fma16(float x0, float x1, float x2, float x3,
                                      const float* __restrict__ w0,
                                      float* __restrict__ acc) {
    #pragma unroll
    for (int j = 0; j < 16; ++j) acc[j] = fmaf(x0, w0[j],       acc[j]);
    #pragma unroll
    for (int j = 0; j < 16; ++j) acc[j] = fmaf(x1, w0[64 + j],  acc[j]);
    #pragma unroll
    for (int j = 0; j < 16; ++j) acc[j] = fmaf(x2, w0[128 + j], acc[j]);
    #pragma unroll
    for (int j = 0; j < 16; ++j) acc[j] = fmaf(x3, w0[192 + j], acc[j]);
}

__global__ __launch_bounds__(THREADS) void node_net_kernel(
    const float* __restrict__ feat, const float* __restrict__ hid,
    const float* __restrict__ mail,
    const float* __restrict__ w1a, const float* __restrict__ b1a,
    const float* __restrict__ w1b, const float* __restrict__ b1b,
    const float* __restrict__ w2a, const float* __restrict__ b2a,
    const float* __restrict__ w2b, const float* __restrict__ b2b,
    float* __restrict__ out)
{
    __shared__ unsigned ldsA[NB * X1SU];   // x1 f16, later h1 f16
    __shared__ float    ldsB[NB * X2S];    // x2, later h2 (f32)
    __shared__ float    ldsS[NB * 4];      // per-sub partial sumsq

    const int t  = threadIdx.x;
    const int n0 = blockIdx.x * NB;
    const int c4 = t & 15;             // float4 column 0..15
    const int nb = t >> 4;             // node base 0..15; owns nodes nb+16c (mailbox/staging)

    // mailbox chain bases: [N][16][64] -> node stride 256 f4, depth stride 16 f4
    const float4* mb0 = reinterpret_cast<const float4*>(mail) + (size_t)(n0 + nb) * 256 + c4;

    // ---------- Phase 1: stage x1 = [feat|hid] as f16 ----------
    #pragma unroll
    for (int i = 0; i < 4; ++i) {
        int n = nb + 16 * i;
        float4 f = reinterpret_cast<const float4*>(feat)[(size_t)(n0 + n) * 16 + c4];
        float4 g = reinterpret_cast<const float4*>(hid )[(size_t)(n0 + n) * 16 + c4];
        unsigned* dst = &ldsA[n * X1SU];
        *reinterpret_cast<uint2*>(dst + c4 * 2)      = make_uint2(pk16(f.x, f.y), pk16(f.z, f.w));
        *reinterpret_cast<uint2*>(dst + 32 + c4 * 2) = make_uint2(pk16(g.x, g.y), pk16(g.z, g.w));
    }
    __syncthreads();                       // B1: x1 visible

    const int node = t & 63;
    const int sub  = __builtin_amdgcn_readfirstlane(t >> 6);  // wave id 0..3, uniform

    // ---------- Phase 2: h1 = relu(x1 @ w1a + b1a), j-slice of 24,
    //            with mailbox streaming pinned under the FMA stream ----------
    float acc1[24];
    {
        const float* b = b1a + sub * 24;
        #pragma unroll
        for (int j = 0; j < 24; ++j) acc1[j] = b[j];
    }
    {
        const unsigned* xr = &ldsA[node * X1SU];
        #pragma unroll 1
        for (int c = 0; c < 4; ++c) {                      // chain c: node nb+16c
            const float4* chain = mb0 + (size_t)c * 4096;  // 16 nodes * 256 f4
            float4 m;
            #pragma unroll
            for (int half = 0; half < 2; ++half) {         // depth slots [8*half, 8*half+8)
                float4 cur[8];
                #pragma unroll
                for (int d = 0; d < 8; ++d) {
                    // depth-rotation swizzle: slot -> actual depth (order-invariant sum)
                    int de = (half * 8 + d + nb) & 15;
                    cur[d] = chain[de * 16];
                }
                __builtin_amdgcn_sched_barrier(0);         // pin: loads issued above
                // 4 k4-iterations (384 FMAs) run while the 8 loads are in flight
                #pragma unroll
                for (int kk = 0; kk < 4; ++kk) {
                    int k4 = (c * 2 + half) * 4 + kk;
                    uint2 xu = *reinterpret_cast<const uint2*>(xr + 2 * k4);
                    half2_t p0 = __builtin_bit_cast(half2_t, xu.x);
                    half2_t p1 = __builtin_bit_cast(half2_t, xu.y);
                    fma24((float)p0.x, (float)p0.y, (float)p1.x, (float)p1.y,
                          w1a + (k4 * 4) * 96 + sub * 24, acc1);
                }
                __builtin_amdgcn_sched_barrier(0);         // pin: consume below FMAs
                float4 s = ((cur[0] + cur[1]) + (cur[2] + cur[3]))
                         + ((cur[4] + cur[5]) + (cur[6] + cur[7]));
                if (half == 0) m = s; else m += s;         // static (half unrolled)
            }
            // x2 row for node nb+16c done; ldsB untouched until after barrier B2
            *reinterpret_cast<float4*>(&ldsB[(nb + 16 * c) * X2S + c4 * 4]) = m;
        }
    }
    __syncthreads();                     // B2: all x1 reads done; reuse ldsA for h1
    {
        unsigned* hv = &ldsA[node * H1SU + sub * 12];
        #pragma unroll
        for (int p = 0; p < 12; ++p)
            hv[p] = pk16(fmaxf(acc1[2*p], 0.f), fmaxf(acc1[2*p + 1], 0.f));
    }
    __syncthreads();                     // B3: h1 visible

    // ---------- Phase 3: r1 = tanh(h1 @ w1b + b1b), j-slice of 16 ----------
    float r1v[16];
    {
        float acc[16];
        const float* b = b1b + sub * 16;
        #pragma unroll
        for (int j = 0; j < 16; ++j) acc[j] = b[j];
        const unsigned* hb = &ldsA[node * H1SU];
        #pragma unroll 2
        for (int k4 = 0; k4 < 24; ++k4) {
            uint2 hu = *reinterpret_cast<const uint2*>(hb + 2 * k4);
            half2_t p0 = __builtin_bit_cast(half2_t, hu.x);
            half2_t p1 = __builtin_bit_cast(half2_t, hu.y);
            fma16((float)p0.x, (float)p0.y, (float)p1.x, (float)p1.y,
                  w1b + (k4 * 4) * 64 + sub * 16, acc);
        }
        #pragma unroll
        for (int j = 0; j < 16; ++j) r1v[j] = fast_tanh(acc[j]);
    }

    // ---------- Phase 4: h2 = relu(x2 @ w2a + b2a), j-slice of 16 ----------
    float h2v[16];
    {
        float acc[16];
        const float* b = b2a + sub * 16;
        #pragma unroll
        for (int j = 0; j < 16; ++j) acc[j] = b[j];
        const float4* xr = reinterpret_cast<const float4*>(&ldsB[node * X2S]);
        #pragma unroll 2
        for (int k4 = 0; k4 < 16; ++k4) {
            float4 x = xr[k4];
            fma16(x.x, x.y, x.z, x.w, w2a + (k4 * 4) * 64 + sub * 16, acc);
        }
        #pragma unroll
        for (int j = 0; j < 16; ++j) h2v[j] = fmaxf(acc[j], 0.f);
    }
    __syncthreads();                     // B4: x2 reads done; reuse ldsB for h2
    {
        float4* hrow = reinterpret_cast<float4*>(&ldsB[node * X2S + sub * 16]);
        hrow[0] = make_float4(h2v[0],  h2v[1],  h2v[2],  h2v[3]);
        hrow[1] = make_float4(h2v[4],  h2v[5],  h2v[6],  h2v[7]);
        hrow[2] = make_float4(h2v[8],  h2v[9],  h2v[10], h2v[11]);
        hrow[3] = make_float4(h2v[12], h2v[13], h2v[14], h2v[15]);
    }
    __syncthreads();                     // B5: h2 visible

    // ---------- Phase 5: r2 = tanh(h2 @ w2b + b2b), j-slice of 16 ----------
    float r2v[16];
    {
        float acc[16];
        const float* b = b2b + sub * 16;
        #pragma unroll
        for (int j = 0; j < 16; ++j) acc[j] = b[j];
        const float4* hr = reinterpret_cast<const float4*>(&ldsB[node * X2S]);
        #pragma unroll 2
        for (int k4 = 0; k4 < 16; ++k4) {
            float4 x = hr[k4];
            fma16(x.x, x.y, x.z, x.w, w2b + (k4 * 4) * 64 + sub * 16, acc);
        }
        #pragma unroll
        for (int j = 0; j < 16; ++j) r2v[j] = fast_tanh(acc[j]);
    }

    // ---------- Phase 6: row L2 norm + write ----------
    float s = 0.f;
    #pragma unroll
    for (int j = 0; j < 16; ++j) s = fmaf(r1v[j], r1v[j], s);
    #pragma unroll
    for (int j = 0; j < 16; ++j) s = fmaf(r2v[j], r2v[j], s);
    ldsS[node * 4 + sub] = s;
    __syncthreads();                     // B6
    float4 sv = reinterpret_cast<const float4*>(ldsS)[node];
    float rn = rsqrtf(sv.x + sv.y + sv.z + sv.w);

    float* orow = out + (size_t)(n0 + node) * 128;
    float4* o1 = reinterpret_cast<float4*>(orow + sub * 16);
    float4* o2 = reinterpret_cast<float4*>(orow + 64 + sub * 16);
    #pragma unroll
    for (int j4 = 0; j4 < 4; ++j4) {
        o1[j4] = make_float4(r1v[j4*4+0]*rn, r1v[j4*4+1]*rn, r1v[j4*4+2]*rn, r1v[j4*4+3]*rn);
        o2[j4] = make_float4(r2v[j4*4+0]*rn, r2v[j4*4+1]*rn, r2v[j4*4+2]*rn, r2v[j4*4+3]*rn);
    }
}

extern "C" void kernel_launch(void* const* d_in, const int* in_sizes, int n_in,
                              void* d_out, int out_size, void* d_ws, size_t ws_size,
                              hipStream_t stream) {
    const float* feat = (const float*)d_in[0];
    const float* hid  = (const float*)d_in[1];
    const float* mail = (const float*)d_in[2];
    const float* w1a  = (const float*)d_in[3];
    const float* b1a  = (const float*)d_in[4];
    const float* w1b  = (const float*)d_in[5];
    const float* b1b  = (const float*)d_in[6];
    const float* w2a  = (const float*)d_in[7];
    const float* b2a  = (const float*)d_in[8];
    const float* w2b  = (const float*)d_in[9];
    const float* b2b  = (const float*)d_in[10];
    float* out = (float*)d_out;

    const int N = in_sizes[0] / 64;          // 200000
    const int blocks = N / NB;               // 3125

    node_net_kernel<<<blocks, THREADS, 0, stream>>>(
        feat, hid, mail, w1a, b1a, w1b, b1b, w2a, b2a, w2b, b2b, out);
}

// Round 12
// 231.973 us; speedup vs baseline: 3.7413x; 1.1562x over previous
//
#include <hip/hip_runtime.h>

// NodeNetwork fused kernel, R8 base (239.9us proven) + v_dot2_f32_f16 GEMMs:
// all matmul operands f16-packed (x1/h1 in ldsA since R8; x2/h2 now too);
// weights pre-packed to f16 pairs in d_ws by a tiny pre-kernel. Halves the
// FMA instruction stream (6656 fma -> 3328 dot2 per thread), shrinking the
// memory-dead P3-P6 tail. f32 accumulate throughout (accuracy-safe).
// No launch_bounds min-waves (R7 lesson). sched_barrier-pinned batches (R4).
constexpr int NB = 64;
constexpr int THREADS = 256;
constexpr int X1SU = 66;   // x1 row stride in u32 (128 f16 + 4 pad)
constexpr int H1SU = 50;   // h1 row stride in u32 (96 f16 + 4 pad), aliases x1 region
constexpr int X2SU = 35;   // x2/h2 row stride in u32 (64 f16 = 32 u32 + 3 pad; odd -> conflict-free)

// packed-weight layout in d_ws (u32 = 2 f16, pairs along k):
constexpr int W1A_OFF = 0;      // 64 k2-rows x 96 j
constexpr int W1B_OFF = 6144;   // 48 x 64
constexpr int W2A_OFF = 9216;   // 32 x 64
constexpr int W2B_OFF = 11264;  // 32 x 64
constexpr int WTOTAL  = 13312;

typedef __fp16 half2_t __attribute__((ext_vector_type(2)));

__device__ __forceinline__ float fast_tanh(float x) {
    // tanh(x) = 1 - 2/(exp(2x)+1); v_exp+v_rcp, abs err ~1e-6, saturates to +-1.
    float e = __expf(2.0f * x);
    return 1.0f - 2.0f * __builtin_amdgcn_rcpf(e + 1.0f);
}

__device__ __forceinline__ unsigned pk16(float a, float b) {
    half2_t h = __builtin_amdgcn_cvt_pkrtz(a, b);
    return __builtin_bit_cast(unsigned, h);
}

__device__ __forceinline__ half2_t uh(unsigned u) {
    return __builtin_bit_cast(half2_t, u);
}

// acc[j] += pa . w0[j] + pb . w1[j]   (24 outputs, 2 k-pairs)
__device__ __forceinline__ void dot24(half2_t pa, half2_t pb,
                                      const unsigned* __restrict__ w0,
                                      const unsigned* __restrict__ w1,
                                      float* __restrict__ acc) {
    #pragma unroll
    for (int j = 0; j < 24; ++j) acc[j] = __builtin_amdgcn_fdot2(pa, uh(w0[j]), acc[j], false);
    #pragma unroll
    for (int j = 0; j < 24; ++j) acc[j] = __builtin_amdgcn_fdot2(pb, uh(w1[j]), acc[j], false);
}

__device__ __forceinline__ void dot16(half2_t pa, half2_t pb,
                                      const unsigned* __restrict__ w0,
                                      const unsigned* __restrict__ w1,
                                      float* __restrict__ acc) {
    #pragma unroll
    for (int j = 0; j < 16; ++j) acc[j] = __builtin_amdgcn_fdot2(pa, uh(w0[j]), acc[j], false);
    #pragma unroll
    for (int j = 0; j < 16; ++j) acc[j] = __builtin_amdgcn_fdot2(pb, uh(w1[j]), acc[j], false);
}

// ---- pre-kernel: pack f32 weights into f16 pairs (along k) in d_ws ----
__global__ __launch_bounds__(256) void cvt_weights(
    const float* __restrict__ w1a, const float* __restrict__ w1b,
    const float* __restrict__ w2a, const float* __restrict__ w2b,
    unsigned* __restrict__ wp)
{
    int idx = blockIdx.x * 256 + threadIdx.x;    // 0..13311
    const float* src; int cols, rel;
    if (idx < W1B_OFF)      { rel = idx;           src = w1a; cols = 96; }
    else if (idx < W2A_OFF) { rel = idx - W1B_OFF; src = w1b; cols = 64; }
    else if (idx < W2B_OFF) { rel = idx - W2A_OFF; src = w2a; cols = 64; }
    else                    { rel = idx - W2B_OFF; src = w2b; cols = 64; }
    int k2 = rel / cols, j = rel - k2 * cols;
    wp[idx] = pk16(src[(2 * k2) * cols + j], src[(2 * k2 + 1) * cols + j]);
}

__global__ __launch_bounds__(THREADS) void node_net_kernel(
    const float* __restrict__ feat, const float* __restrict__ hid,
    const float* __restrict__ mail,
    const float* __restrict__ b1a, const float* __restrict__ b1b,
    const float* __restrict__ b2a, const float* __restrict__ b2b,
    const unsigned* __restrict__ wp,
    float* __restrict__ out)
{
    __shared__ unsigned ldsA[NB * X1SU];   // x1 f16, later h1 f16
    __shared__ unsigned ldsB[NB * X2SU];   // x2 f16, later h2 f16
    __shared__ float    ldsS[NB * 4];      // per-sub partial sumsq

    const int t  = threadIdx.x;
    const int n0 = blockIdx.x * NB;
    const int c4 = t & 15;             // float4 column 0..15
    const int nb = t >> 4;             // node base 0..15; owns nodes nb+16c (mailbox/staging)

    // mailbox chain bases: [N][16][64] -> node stride 256 f4, depth stride 16 f4
    const float4* mb0 = reinterpret_cast<const float4*>(mail) + (size_t)(n0 + nb) * 256 + c4;

    // ---------- Phase 1: stage x1 = [feat|hid] as f16 ----------
    #pragma unroll
    for (int i = 0; i < 4; ++i) {
        int n = nb + 16 * i;
        float4 f = reinterpret_cast<const float4*>(feat)[(size_t)(n0 + n) * 16 + c4];
        float4 g = reinterpret_cast<const float4*>(hid )[(size_t)(n0 + n) * 16 + c4];
        unsigned* dst = &ldsA[n * X1SU];
        *reinterpret_cast<uint2*>(dst + c4 * 2)      = make_uint2(pk16(f.x, f.y), pk16(f.z, f.w));
        *reinterpret_cast<uint2*>(dst + 32 + c4 * 2) = make_uint2(pk16(g.x, g.y), pk16(g.z, g.w));
    }
    __syncthreads();                       // B1: x1 visible

    const int node = t & 63;
    const int sub  = __builtin_amdgcn_readfirstlane(t >> 6);  // wave id 0..3, uniform

    // ---------- Phase 2: h1 = relu(x1 @ w1a + b1a), j-slice of 24,
    //            with mailbox streaming pinned under the dot2 stream ----------
    float acc1[24];
    {
        const float* b = b1a + sub * 24;
        #pragma unroll
        for (int j = 0; j < 24; ++j) acc1[j] = b[j];
    }
    {
        const unsigned* xr = &ldsA[node * X1SU];
        const unsigned* w1aP = wp + W1A_OFF + sub * 24;
        #pragma unroll 1
        for (int c = 0; c < 4; ++c) {                      // chain c: node nb+16c
            const float4* chain = mb0 + (size_t)c * 4096;  // 16 nodes * 256 f4
            float4 m;
            #pragma unroll
            for (int half = 0; half < 2; ++half) {         // depths [8*half, 8*half+8)
                float4 cur[8];
                #pragma unroll
                for (int d = 0; d < 8; ++d)
                    cur[d] = chain[(half * 8 + d) * 16];
                __builtin_amdgcn_sched_barrier(0);         // pin: loads issued above
                // 4 k4-iterations (192 dot2) run while the 8 loads are in flight
                #pragma unroll
                for (int kk = 0; kk < 4; ++kk) {
                    int k4 = (c * 2 + half) * 4 + kk;
                    uint2 xu = *reinterpret_cast<const uint2*>(xr + 2 * k4);
                    dot24(uh(xu.x), uh(xu.y),
                          w1aP + (2 * k4) * 96, w1aP + (2 * k4 + 1) * 96, acc1);
                }
                __builtin_amdgcn_sched_barrier(0);         // pin: consume below
                float4 s = ((cur[0] + cur[1]) + (cur[2] + cur[3]))
                         + ((cur[4] + cur[5]) + (cur[6] + cur[7]));
                if (half == 0) m = s; else m += s;         // static (half unrolled)
            }
            // x2 row (f16 pairs) for node nb+16c; ldsB untouched until after B2
            *reinterpret_cast<uint2*>(&ldsB[(nb + 16 * c) * X2SU + c4 * 2]) =
                make_uint2(pk16(m.x, m.y), pk16(m.z, m.w));
        }
    }
    __syncthreads();                     // B2: all x1 reads done; reuse ldsA for h1
    {
        unsigned* hv = &ldsA[node * H1SU + sub * 12];
        #pragma unroll
        for (int p = 0; p < 12; ++p)
            hv[p] = pk16(fmaxf(acc1[2*p], 0.f), fmaxf(acc1[2*p + 1], 0.f));
    }
    __syncthreads();                     // B3: h1 visible

    // ---------- Phase 3: r1 = tanh(h1 @ w1b + b1b), j-slice of 16 ----------
    float r1v[16];
    {
        float acc[16];
        const float* b = b1b + sub * 16;
        #pragma unroll
        for (int j = 0; j < 16; ++j) acc[j] = b[j];
        const unsigned* hb = &ldsA[node * H1SU];
        const unsigned* w1bP = wp + W1B_OFF + sub * 16;
        #pragma unroll 2
        for (int k4 = 0; k4 < 24; ++k4) {
            uint2 hu2 = *reinterpret_cast<const uint2*>(hb + 2 * k4);
            dot16(uh(hu2.x), uh(hu2.y),
                  w1bP + (2 * k4) * 64, w1bP + (2 * k4 + 1) * 64, acc);
        }
        #pragma unroll
        for (int j = 0; j < 16; ++j) r1v[j] = fast_tanh(acc[j]);
    }

    // ---------- Phase 4: h2 = relu(x2 @ w2a + b2a), j-slice of 16 ----------
    float h2v[16];
    {
        float acc[16];
        const float* b = b2a + sub * 16;
        #pragma unroll
        for (int j = 0; j < 16; ++j) acc[j] = b[j];
        const unsigned* xb = &ldsB[node * X2SU];
        const unsigned* w2aP = wp + W2A_OFF + sub * 16;
        #pragma unroll 2
        for (int k4 = 0; k4 < 16; ++k4) {
            uint2 xu = *reinterpret_cast<const uint2*>(xb + 2 * k4);
            dot16(uh(xu.x), uh(xu.y),
                  w2aP + (2 * k4) * 64, w2aP + (2 * k4 + 1) * 64, acc);
        }
        #pragma unroll
        for (int j = 0; j < 16; ++j) h2v[j] = fmaxf(acc[j], 0.f);
    }
    __syncthreads();                     // B4: x2 reads done; reuse ldsB for h2
    {
        unsigned* hrow = &ldsB[node * X2SU + sub * 8];
        #pragma unroll
        for (int p = 0; p < 8; ++p)
            hrow[p] = pk16(h2v[2*p], h2v[2*p + 1]);
    }
    __syncthreads();                     // B5: h2 visible

    // ---------- Phase 5: r2 = tanh(h2 @ w2b + b2b), j-slice of 16 ----------
    float r2v[16];
    {
        float acc[16];
        const float* b = b2b + sub * 16;
        #pragma unroll
        for (int j = 0; j < 16; ++j) acc[j] = b[j];
        const unsigned* hb2 = &ldsB[node * X2SU];
        const unsigned* w2bP = wp + W2B_OFF + sub * 16;
        #pragma unroll 2
        for (int k4 = 0; k4 < 16; ++k4) {
            uint2 xu = *reinterpret_cast<const uint2*>(hb2 + 2 * k4);
            dot16(uh(xu.x), uh(xu.y),
                  w2bP + (2 * k4) * 64, w2bP + (2 * k4 + 1) * 64, acc);
        }
        #pragma unroll
        for (int j = 0; j < 16; ++j) r2v[j] = fast_tanh(acc[j]);
    }

    // ---------- Phase 6: row L2 norm + write ----------
    float s = 0.f;
    #pragma unroll
    for (int j = 0; j < 16; ++j) s = fmaf(r1v[j], r1v[j], s);
    #pragma unroll
    for (int j = 0; j < 16; ++j) s = fmaf(r2v[j], r2v[j], s);
    ldsS[node * 4 + sub] = s;
    __syncthreads();                     // B6
    float4 sv = reinterpret_cast<const float4*>(ldsS)[node];
    float rn = rsqrtf(sv.x + sv.y + sv.z + sv.w);

    float* orow = out + (size_t)(n0 + node) * 128;
    float4* o1 = reinterpret_cast<float4*>(orow + sub * 16);
    float4* o2 = reinterpret_cast<float4*>(orow + 64 + sub * 16);
    #pragma unroll
    for (int j4 = 0; j4 < 4; ++j4) {
        o1[j4] = make_float4(r1v[j4*4+0]*rn, r1v[j4*4+1]*rn, r1v[j4*4+2]*rn, r1v[j4*4+3]*rn);
        o2[j4] = make_float4(r2v[j4*4+0]*rn, r2v[j4*4+1]*rn, r2v[j4*4+2]*rn, r2v[j4*4+3]*rn);
    }
}

extern "C" void kernel_launch(void* const* d_in, const int* in_sizes, int n_in,
                              void* d_out, int out_size, void* d_ws, size_t ws_size,
                              hipStream_t stream) {
    const float* feat = (const float*)d_in[0];
    const float* hid  = (const float*)d_in[1];
    const float* mail = (const float*)d_in[2];
    const float* w1a  = (const float*)d_in[3];
    const float* b1a  = (const float*)d_in[4];
    const float* w1b  = (const float*)d_in[5];
    const float* b1b  = (const float*)d_in[6];
    const float* w2a  = (const float*)d_in[7];
    const float* b2a  = (const float*)d_in[8];
    const float* w2b  = (const float*)d_in[9];
    const float* b2b  = (const float*)d_in[10];
    float* out = (float*)d_out;
    unsigned* wp = (unsigned*)d_ws;          // 13312 u32 = 53KB packed f16 weights

    const int N = in_sizes[0] / 64;          // 200000
    const int blocks = N / NB;               // 3125

    cvt_weights<<<WTOTAL / 256, 256, 0, stream>>>(w1a, w1b, w2a, w2b, wp);
    node_net_kernel<<<blocks, THREADS, 0, stream>>>(
        feat, hid, mail, b1a, b1b, b2a, b2b, wp, out);
}